// Round 5
// baseline (434.696 us; speedup 1.0000x reference)
//
#include <hip/hip_runtime.h>
#include <hip/hip_bf16.h>
#include <stdint.h>

typedef unsigned short u16;
typedef short s16x8 __attribute__((ext_vector_type(8)));
typedef u16 u16x8 __attribute__((ext_vector_type(8)));
typedef u16 u16x4 __attribute__((ext_vector_type(4)));
typedef float f32x4 __attribute__((ext_vector_type(4)));

__device__ __forceinline__ u16 f2bf(float f) {
  union { float f; uint32_t u; } c; c.f = f;
  uint32_t u = c.u;
  u = u + 0x7fffu + ((u >> 16) & 1u);   // round-to-nearest-even
  return (u16)(u >> 16);
}
__device__ __forceinline__ float bf2f(u16 b) {
  union { uint32_t u; float f; } c; c.u = ((uint32_t)b) << 16;
  return c.f;
}

// async global->LDS, 16B per lane. LDS dest must be wave-uniform base + lane*16.
__device__ __forceinline__ void gld_lds16(const u16* g, u16* l) {
  __builtin_amdgcn_global_load_lds(
      (const __attribute__((address_space(1))) uint32_t*)g,
      (__attribute__((address_space(3))) uint32_t*)l,
      16, 0, 0);
}

// ---------------------------------------------------------------------------
// fp32 -> bf16 convert, 8 elems/thread; single-source version
// ---------------------------------------------------------------------------
__global__ __launch_bounds__(256) void cvt_f32_to_bf16(
    const float* __restrict__ in, u16* __restrict__ out, long n8) {
  long i = (long)blockIdx.x * blockDim.x + threadIdx.x;
  if (i >= n8) return;
  const float4 a = ((const float4*)in)[i * 2];
  const float4 b = ((const float4*)in)[i * 2 + 1];
  u16x8 r;
  r[0] = f2bf(a.x); r[1] = f2bf(a.y); r[2] = f2bf(a.z); r[3] = f2bf(a.w);
  r[4] = f2bf(b.x); r[5] = f2bf(b.y); r[6] = f2bf(b.z); r[7] = f2bf(b.w);
  *(u16x8*)&out[i * 8] = r;
}

// 4 weight matrices (1024x1024 each) in one launch: blockIdx.y selects src
__global__ __launch_bounds__(256) void cvt_w4(
    const float* __restrict__ w0, const float* __restrict__ w1,
    const float* __restrict__ w2, const float* __restrict__ w3,
    u16* __restrict__ out) {
  const float* src = (blockIdx.y == 0) ? w0 : (blockIdx.y == 1) ? w1
                   : (blockIdx.y == 2) ? w2 : w3;
  const long i = (long)blockIdx.x * blockDim.x + threadIdx.x;
  const float4 a = ((const float4*)src)[i * 2];
  const float4 b = ((const float4*)src)[i * 2 + 1];
  u16x8 r;
  r[0] = f2bf(a.x); r[1] = f2bf(a.y); r[2] = f2bf(a.z); r[3] = f2bf(a.w);
  r[4] = f2bf(b.x); r[5] = f2bf(b.y); r[6] = f2bf(b.z); r[7] = f2bf(b.w);
  *(u16x8*)&out[(long)blockIdx.y * 1048576 + i * 8] = r;
}

// ---------------------------------------------------------------------------
// masked row softmax over 2048 cols, bf16 in/out (in place), fp32 math.
// ---------------------------------------------------------------------------
__global__ __launch_bounds__(256) void softmax_mask_rows(
    u16* __restrict__ S, const int* __restrict__ mask) {
  const long base = (long)blockIdx.x * 2048;
  const int tid = threadIdx.x;
  const int lane = tid & 63, wave = tid >> 6;
  u16x8 raw = *(const u16x8*)&S[base + tid * 8];
  const int4 m0 = ((const int4*)(mask + base))[tid * 2];
  const int4 m1 = ((const int4*)(mask + base))[tid * 2 + 1];
  float v[8];
  v[0] = m0.x ? bf2f(raw[0]) : -1e30f;
  v[1] = m0.y ? bf2f(raw[1]) : -1e30f;
  v[2] = m0.z ? bf2f(raw[2]) : -1e30f;
  v[3] = m0.w ? bf2f(raw[3]) : -1e30f;
  v[4] = m1.x ? bf2f(raw[4]) : -1e30f;
  v[5] = m1.y ? bf2f(raw[5]) : -1e30f;
  v[6] = m1.z ? bf2f(raw[6]) : -1e30f;
  v[7] = m1.w ? bf2f(raw[7]) : -1e30f;
  float m = v[0];
#pragma unroll
  for (int j = 1; j < 8; ++j) m = fmaxf(m, v[j]);
#pragma unroll
  for (int off = 32; off >= 1; off >>= 1) m = fmaxf(m, __shfl_xor(m, off));
  __shared__ float red[8];
  if (lane == 0) red[wave] = m;
  __syncthreads();
  m = fmaxf(fmaxf(red[0], red[1]), fmaxf(red[2], red[3]));
  float s = 0.f;
#pragma unroll
  for (int j = 0; j < 8; ++j) { v[j] = __expf(v[j] - m); s += v[j]; }
#pragma unroll
  for (int off = 32; off >= 1; off >>= 1) s += __shfl_xor(s, off);
  if (lane == 0) red[4 + wave] = s;
  __syncthreads();
  s = (red[4] + red[5]) + (red[6] + red[7]);
  const float inv = 1.f / s;
#pragma unroll
  for (int j = 0; j < 8; ++j) raw[j] = f2bf(v[j] * inv);
  *(u16x8*)&S[base + tid * 8] = raw;
}

// ---------------------------------------------------------------------------
// 256x256x64 8-phase GEMM (bt): C[b][m][n] = sum_k A[b][m][k]*B[b][n][k].
// 512 thr = 8 waves (2M x 4N); LDS 128 KiB 2x dbuf; T2 chunk-XOR swizzle;
// T1 XCD-bijective block remap; counted vmcnt(4) at tile boundary only.
// Register-held fragments, gray-code phase order (0,0)->(0,1)->(1,1)->(1,0):
//   ph1: load af0(8)+bg0(4); stage Al(t+1)->nxt ; MFMA(0,0)
//   ph2: load bg1(4);        stage Bl(t+1)->nxt ; MFMA(0,1)
//   ph3: load af1(8);        stage Ae(t+2)->cur ; MFMA(1,1)
//   ph4: (no loads)          stage Be(t+2)->cur ; MFMA(1,0); vmcnt(4)
// Hazard proof: every staged region's last ds_read drained (per-wave lgkm
// before own MFMA) >=1 closing barrier before the overwriting DMA issues;
// vmcnt(4) leaves exactly Ae(t+2),Be(t+2) in flight; tile t+1 resident.
// MODE: 0 = bf16 out; 1 = f32 out; 2 = split KV (cols<1024 -> Cv bf16
// ldC=1024; cols>=1024 -> Cv2 transposed bf16 [batch][col][2048-row]).
// ---------------------------------------------------------------------------
__device__ __forceinline__ s16x8 ldsfrag(const u16* p, int r, int c8) {
  return *(const s16x8*)&p[r * 64 + ((c8 ^ (r & 7)) << 3)];
}

template<int MAT, int LATE>
__device__ __forceinline__ void stage_chunk(const u16* __restrict__ gb, int row0,
                                            int K, int k0, u16* lbuf, int tid) {
#pragma unroll
  for (int i = 0; i < 2; ++i) {
    const int f = i * 512 + tid;
    const int rl = f >> 3, s = f & 7;
    int r;
    if (MAT == 0) r = (rl & 63) + ((rl >> 6) << 7) + (LATE ? 64 : 0);
    else          r = (rl & 31) + ((rl >> 5) << 6) + (LATE ? 32 : 0);
    const int gc = (s ^ (r & 7)) << 3;      // pre-swizzled global col chunk
    gld_lds16(gb + (long)(row0 + r) * K + k0 + gc, lbuf + r * 64 + s * 8);
  }
}

#define GFENCE asm volatile("" ::: "memory")

template<int QM>
__device__ __forceinline__ void load_af(s16x8 (&a)[4][2], const u16* lA,
                                        int wm, int lr, int lk) {
#pragma unroll
  for (int mi = 0; mi < 4; ++mi)
#pragma unroll
    for (int ks = 0; ks < 2; ++ks)
      a[mi][ks] = ldsfrag(lA, wm * 128 + QM * 64 + mi * 16 + lr, ks * 4 + lk);
}
template<int QN>
__device__ __forceinline__ void load_bg(s16x8 (&bb)[2][2], const u16* lB,
                                        int wn, int lr, int lk) {
#pragma unroll
  for (int ni = 0; ni < 2; ++ni)
#pragma unroll
    for (int ks = 0; ks < 2; ++ks)
      bb[ni][ks] = ldsfrag(lB, wn * 64 + QN * 32 + ni * 16 + lr, ks * 4 + lk);
}
template<int QM, int QN>
__device__ __forceinline__ void mfma16(f32x4 (&acc)[8][4],
                                       const s16x8 (&a)[4][2],
                                       const s16x8 (&bb)[2][2]) {
  GFENCE; __builtin_amdgcn_s_barrier(); GFENCE;
  __builtin_amdgcn_s_setprio(1);
#pragma unroll
  for (int mi = 0; mi < 4; ++mi)
#pragma unroll
    for (int ni = 0; ni < 2; ++ni) {
      acc[QM * 4 + mi][QN * 2 + ni] = __builtin_amdgcn_mfma_f32_16x16x32_bf16(
          a[mi][0], bb[ni][0], acc[QM * 4 + mi][QN * 2 + ni], 0, 0, 0);
      acc[QM * 4 + mi][QN * 2 + ni] = __builtin_amdgcn_mfma_f32_16x16x32_bf16(
          a[mi][1], bb[ni][1], acc[QM * 4 + mi][QN * 2 + ni], 0, 0, 0);
    }
  __builtin_amdgcn_s_setprio(0);
}
#define PH_CLOSE do { GFENCE; __builtin_amdgcn_s_barrier(); GFENCE; } while (0)

template<int CUR>
__device__ __forceinline__ void tile_body(
    int t, int NT, const u16* __restrict__ Ab, const u16* __restrict__ Bb,
    int bm, int bn, int K, u16 (&lds)[2][2][256 * 64], f32x4 (&acc)[8][4],
    int wm, int wn, int lr, int lk, int tid) {
  const u16* lA = lds[CUR][0];
  const u16* lB = lds[CUR][1];
  u16* nA = lds[CUR ^ 1][0];
  u16* nB = lds[CUR ^ 1][1];
  u16* cA = lds[CUR][0];
  u16* cB = lds[CUR][1];
  const int k1 = (t + 1) << 6, k2 = (t + 2) << 6;
  s16x8 af0[4][2], af1[4][2], bg0[2][2], bg1[2][2];
  // ph1 (0,0)
  load_af<0>(af0, lA, wm, lr, lk);
  load_bg<0>(bg0, lB, wn, lr, lk);
  if (t + 1 < NT) stage_chunk<0, 1>(Ab, bm, K, k1, nA, tid);
  mfma16<0, 0>(acc, af0, bg0);
  PH_CLOSE;
  // ph2 (0,1)
  load_bg<1>(bg1, lB, wn, lr, lk);
  if (t + 1 < NT) stage_chunk<1, 1>(Bb, bn, K, k1, nB, tid);
  mfma16<0, 1>(acc, af0, bg1);
  PH_CLOSE;
  // ph3 (1,1)
  load_af<1>(af1, lA, wm, lr, lk);
  if (t + 2 < NT) stage_chunk<0, 0>(Ab, bm, K, k2, cA, tid);
  mfma16<1, 1>(acc, af1, bg1);
  PH_CLOSE;
  // ph4 (1,0) — no ds_reads
  if (t + 2 < NT) stage_chunk<1, 0>(Bb, bn, K, k2, cB, tid);
  mfma16<1, 0>(acc, af1, bg0);
  if (t + 2 < NT)      { asm volatile("s_waitcnt vmcnt(4)" ::: "memory"); }
  else if (t + 1 < NT) { asm volatile("s_waitcnt vmcnt(0)" ::: "memory"); }
  PH_CLOSE;
}

template<bool HAS_BIAS, int MODE>
__global__ __launch_bounds__(512, 1) void gemm256(
    const u16* __restrict__ A, const u16* __restrict__ B,
    const float* __restrict__ bias, const float* __restrict__ bias2,
    void* __restrict__ Cv, void* __restrict__ Cv2,
    int M, int N, int K, long sA, long sB, long sC, float scale) {
  __shared__ __align__(16) u16 lds[2][2][256 * 64];
  // T1 swizzle: dispatch id -> XCD-contiguous chunk, z-major then x-major.
  const int nx = gridDim.x, ny = gridDim.y;
  const int did = blockIdx.x + nx * (blockIdx.y + ny * blockIdx.z);
  const int cpx = (nx * ny * gridDim.z) >> 3;       // all grids %8 == 0
  const int nf = (did & 7) * cpx + (did >> 3);
  const int b = nf / (nx * ny);
  const int rr = nf % (nx * ny);
  const int bm = (rr / ny) * 256;
  const int bn = (rr % ny) * 256;

  const u16* Ab = A + (long)b * sA;
  const u16* Bb = B + (long)b * sB;
  const int tid = threadIdx.x;
  const int lane = tid & 63, wave = tid >> 6;
  const int wm = wave >> 2, wn = wave & 3;
  const int lr = lane & 15, lk = lane >> 4;
  const int NT = K >> 6;                              // 16 or 32, always even

  f32x4 acc[8][4] = {};

  // prologue: tile0 all 4 chunks -> buf0, tile1 early chunks -> buf1
  stage_chunk<0, 0>(Ab, bm, K, 0, lds[0][0], tid);
  stage_chunk<1, 0>(Bb, bn, K, 0, lds[0][1], tid);
  stage_chunk<0, 1>(Ab, bm, K, 0, lds[0][0], tid);
  stage_chunk<1, 1>(Bb, bn, K, 0, lds[0][1], tid);
  if (NT > 1) {
    stage_chunk<0, 0>(Ab, bm, K, 64, lds[1][0], tid);
    stage_chunk<1, 0>(Bb, bn, K, 64, lds[1][1], tid);
    asm volatile("s_waitcnt vmcnt(4)" ::: "memory");
  } else {
    asm volatile("s_waitcnt vmcnt(0)" ::: "memory");
  }
  __builtin_amdgcn_s_barrier();
  GFENCE;

  for (int t = 0; t < NT; t += 2) {
    tile_body<0>(t,     NT, Ab, Bb, bm, bn, K, lds, acc, wm, wn, lr, lk, tid);
    tile_body<1>(t + 1, NT, Ab, Bb, bm, bn, K, lds, acc, wm, wn, lr, lk, tid);
  }

  // epilogue: C/D layout col = lane&15, row = (lane>>4)*4 + j
  const bool vside = (MODE == 2) && (bn >= 1024);
  const int ldC = (MODE == 2) ? 1024 : N;
  const long cb = (long)b * sC;
  if (vside) {
    // transposed V store: Cv2[batch][col][row], 2048 rows/batch, ld 2048
#pragma unroll
    for (int mi = 0; mi < 8; ++mi) {
#pragma unroll
      for (int ni = 0; ni < 4; ++ni) {
        const int row0 = bm + wm * 128 + mi * 16 + (lk << 2);
        const int col2 = (bn - 1024) + wn * 64 + ni * 16 + lr;
        const float bvx = HAS_BIAS ? bias2[col2] : 0.f;
        u16x4 pk;
#pragma unroll
        for (int j = 0; j < 4; ++j) pk[j] = f2bf(acc[mi][ni][j] * scale + bvx);
        const long ad = (long)(row0 >> 11) * (2048L * 1024) +
                        (long)col2 * 2048 + (row0 & 2047);
        *(u16x4*)&((u16*)Cv2)[ad] = pk;
      }
    }
  } else {
#pragma unroll
    for (int mi = 0; mi < 8; ++mi) {
#pragma unroll
      for (int ni = 0; ni < 4; ++ni) {
        const int row0 = bm + wm * 128 + mi * 16 + (lk << 2);
        const int col = bn + wn * 64 + ni * 16 + lr;
        const float bvx = HAS_BIAS ? bias[col] : 0.f;
#pragma unroll
        for (int j = 0; j < 4; ++j) {
          const float x = acc[mi][ni][j] * scale + bvx;
          if (MODE == 1)
            ((float*)Cv)[cb + (long)(row0 + j) * ldC + col] = x;
          else
            ((u16*)Cv)[cb + (long)(row0 + j) * ldC + col] = f2bf(x);
        }
      }
    }
  }
}

// ---------------------------------------------------------------------------
extern "C" void kernel_launch(void* const* d_in, const int* in_sizes, int n_in,
                              void* d_out, int out_size, void* d_ws, size_t ws_size,
                              hipStream_t stream) {
  const float* query = (const float*)d_in[0];   // [8,2048,1024]
  const float* kv    = (const float*)d_in[1];   // [8,2048,1024]
  const int*   mask  = (const int*)d_in[2];     // [8,2048,2048]
  const float* Wq = (const float*)d_in[3];
  const float* bq = (const float*)d_in[4];
  const float* Wk = (const float*)d_in[5];
  const float* bk = (const float*)d_in[6];
  const float* Wv = (const float*)d_in[7];
  const float* bv = (const float*)d_in[8];
  const float* Wo = (const float*)d_in[9];
  const float* bo = (const float*)d_in[10];
  float* out = (float*)d_out;

  char* ws = (char*)d_ws;
  const size_t MB = (size_t)1 << 20;
  u16* qbf  = (u16*)(ws + 0);          // 32MB query bf16; later reused as O
  u16* kvbf = (u16*)(ws + 32 * MB);    // 32MB kv bf16
  u16* wq   = (u16*)(ws + 64 * MB);    // 2MB  (wq,wk,wv,wo contiguous)
  u16* wk   = (u16*)(ws + 66 * MB);
  u16* wo   = (u16*)(ws + 70 * MB);
  u16* Q    = (u16*)(ws + 72 * MB);    // 32MB
  u16* Kb   = (u16*)(ws + 104 * MB);   // 32MB
  u16* Vt   = (u16*)(ws + 136 * MB);   // 32MB  [8][1024][2048] bf16
  u16* S    = (u16*)(ws + 168 * MB);   // 64MB  [8][2048][2048] bf16
  u16* O    = qbf;                     // [8][2048][1024] bf16 (qbf dead by then)

  const long sQK = (long)2048 * 1024;
  const long sS  = (long)2048 * 2048;

  // 1) converts
  cvt_f32_to_bf16<<<8192, 256, 0, stream>>>(query, qbf, 2097152);
  cvt_f32_to_bf16<<<8192, 256, 0, stream>>>(kv, kvbf, 2097152);
  cvt_w4<<<dim3(512, 4, 1), 256, 0, stream>>>(Wq, Wk, Wv, Wo, wq);

  // 2) Q projection: M=16384, N=1024, K=1024
  gemm256<true, 0><<<dim3(64, 4, 1), 512, 0, stream>>>(
      qbf, wq, bq, nullptr, Q, nullptr, 16384, 1024, 1024, 0, 0, 0, 1.f);

  // 3) merged K+V projection: N=2048 (B = wk||wv contiguous).
  //    cols<1024 -> Kb [16384][1024]; cols>=1024 -> Vt transposed.
  gemm256<true, 2><<<dim3(64, 8, 1), 512, 0, stream>>>(
      kvbf, wk, bk, bv, Kb, Vt, 16384, 2048, 1024, 0, 0, 0, 1.f);

  // 4) S = (Q K^T) * 1/32 (mask applied in softmax)
  gemm256<false, 0><<<dim3(8, 8, 8), 512, 0, stream>>>(
      Q, Kb, nullptr, nullptr, S, nullptr, 2048, 2048, 1024, sQK, sQK, sS, 0.03125f);

  // 5) masked row softmax (in place on S)
  softmax_mask_rows<<<16384, 256, 0, stream>>>(S, mask);

  // 6) O = P @ V   (B = Vt [1024 n-rows][2048 k], batch stride sQK)
  gemm256<false, 0><<<dim3(8, 4, 8), 512, 0, stream>>>(
      S, Vt, nullptr, nullptr, O, nullptr, 2048, 1024, 2048, sS, sQK, sQK, 1.f);

  // 7) out = O @ Wo^T + bo   (fp32 output)
  gemm256<true, 1><<<dim3(64, 4, 1), 512, 0, stream>>>(
      O, wo, bo, nullptr, out, nullptr, 16384, 1024, 1024, 0, 0, 0, 1.f);
}

// Round 6
// 429.394 us; speedup vs baseline: 1.0123x; 1.0123x over previous
//
#include <hip/hip_runtime.h>
#include <hip/hip_bf16.h>
#include <stdint.h>

typedef unsigned short u16;
typedef short s16x8 __attribute__((ext_vector_type(8)));
typedef u16 u16x8 __attribute__((ext_vector_type(8)));
typedef u16 u16x4 __attribute__((ext_vector_type(4)));
typedef float f32x4 __attribute__((ext_vector_type(4)));

__device__ __forceinline__ u16 f2bf(float f) {
  union { float f; uint32_t u; } c; c.f = f;
  uint32_t u = c.u;
  u = u + 0x7fffu + ((u >> 16) & 1u);   // round-to-nearest-even
  return (u16)(u >> 16);
}
__device__ __forceinline__ float bf2f(u16 b) {
  union { uint32_t u; float f; } c; c.u = ((uint32_t)b) << 16;
  return c.f;
}

// async global->LDS, 16B per lane. LDS dest must be wave-uniform base + lane*16.
__device__ __forceinline__ void gld_lds16(const u16* g, u16* l) {
  __builtin_amdgcn_global_load_lds(
      (const __attribute__((address_space(1))) uint32_t*)g,
      (__attribute__((address_space(3))) uint32_t*)l,
      16, 0, 0);
}

// ---------------------------------------------------------------------------
// fp32 -> bf16 convert, 8 elems/thread
// ---------------------------------------------------------------------------
__global__ __launch_bounds__(256) void cvt_f32_to_bf16(
    const float* __restrict__ in, u16* __restrict__ out, long n8) {
  long i = (long)blockIdx.x * blockDim.x + threadIdx.x;
  if (i >= n8) return;
  const float4 a = ((const float4*)in)[i * 2];
  const float4 b = ((const float4*)in)[i * 2 + 1];
  u16x8 r;
  r[0] = f2bf(a.x); r[1] = f2bf(a.y); r[2] = f2bf(a.z); r[3] = f2bf(a.w);
  r[4] = f2bf(b.x); r[5] = f2bf(b.y); r[6] = f2bf(b.z); r[7] = f2bf(b.w);
  *(u16x8*)&out[i * 8] = r;
}

// 4 weight matrices (1024x1024 each) in one launch: blockIdx.y selects src
__global__ __launch_bounds__(256) void cvt_w4(
    const float* __restrict__ w0, const float* __restrict__ w1,
    const float* __restrict__ w2, const float* __restrict__ w3,
    u16* __restrict__ out) {
  const float* src = (blockIdx.y == 0) ? w0 : (blockIdx.y == 1) ? w1
                   : (blockIdx.y == 2) ? w2 : w3;
  const long i = (long)blockIdx.x * blockDim.x + threadIdx.x;
  const float4 a = ((const float4*)src)[i * 2];
  const float4 b = ((const float4*)src)[i * 2 + 1];
  u16x8 r;
  r[0] = f2bf(a.x); r[1] = f2bf(a.y); r[2] = f2bf(a.z); r[3] = f2bf(a.w);
  r[4] = f2bf(b.x); r[5] = f2bf(b.y); r[6] = f2bf(b.z); r[7] = f2bf(b.w);
  *(u16x8*)&out[(long)blockIdx.y * 1048576 + i * 8] = r;
}

// ---------------------------------------------------------------------------
// masked row softmax over 2048 cols, bf16 in/out (in place), fp32 math.
// ---------------------------------------------------------------------------
__global__ __launch_bounds__(256) void softmax_mask_rows(
    u16* __restrict__ S, const int* __restrict__ mask) {
  const long base = (long)blockIdx.x * 2048;
  const int tid = threadIdx.x;
  const int lane = tid & 63, wave = tid >> 6;
  u16x8 raw = *(const u16x8*)&S[base + tid * 8];
  const int4 m0 = ((const int4*)(mask + base))[tid * 2];
  const int4 m1 = ((const int4*)(mask + base))[tid * 2 + 1];
  float v[8];
  v[0] = m0.x ? bf2f(raw[0]) : -1e30f;
  v[1] = m0.y ? bf2f(raw[1]) : -1e30f;
  v[2] = m0.z ? bf2f(raw[2]) : -1e30f;
  v[3] = m0.w ? bf2f(raw[3]) : -1e30f;
  v[4] = m1.x ? bf2f(raw[4]) : -1e30f;
  v[5] = m1.y ? bf2f(raw[5]) : -1e30f;
  v[6] = m1.z ? bf2f(raw[6]) : -1e30f;
  v[7] = m1.w ? bf2f(raw[7]) : -1e30f;
  float m = v[0];
#pragma unroll
  for (int j = 1; j < 8; ++j) m = fmaxf(m, v[j]);
#pragma unroll
  for (int off = 32; off >= 1; off >>= 1) m = fmaxf(m, __shfl_xor(m, off));
  __shared__ float red[8];
  if (lane == 0) red[wave] = m;
  __syncthreads();
  m = fmaxf(fmaxf(red[0], red[1]), fmaxf(red[2], red[3]));
  float s = 0.f;
#pragma unroll
  for (int j = 0; j < 8; ++j) { v[j] = __expf(v[j] - m); s += v[j]; }
#pragma unroll
  for (int off = 32; off >= 1; off >>= 1) s += __shfl_xor(s, off);
  if (lane == 0) red[4 + wave] = s;
  __syncthreads();
  s = (red[4] + red[5]) + (red[6] + red[7]);
  const float inv = 1.f / s;
#pragma unroll
  for (int j = 0; j < 8; ++j) raw[j] = f2bf(v[j] * inv);
  *(u16x8*)&S[base + tid * 8] = raw;
}

// ---------------------------------------------------------------------------
// 256x256x64 GEMM (bt), 4 phases/K-tile, ONE barrier per phase:
//   ph: [ds_read frags | stage DMA] ; BAR ; [setprio MFMA setprio]
// Hazard proof (1-barrier): each wave's phase-p ds_reads complete (lgkm)
// before its phase-p MFMA, hence before it arrives at barrier p+1; every
// overwriting DMA is issued after a barrier that follows the last reader
// phase's barrier. vmcnt(4) before B4 leaves exactly Ae(t+2),Be(t+2) in
// flight, so tile t+1 is resident when B4 releases.
// Gray-code phases: (0,0)->(0,1)->(1,1)->(1,0); frags register-held:
//   ph1: rd af0+bg0, DMA Al(t+1)->nxt | ph2: rd bg1, DMA Bl(t+1)->nxt
//   ph3: rd af1,     DMA Ae(t+2)->cur | ph4: DMA Be(t+2)->cur, vmcnt(4)
// Epilogue: stage C through LDS (union'd, [128][260] f32) -> coalesced
// 16B row-major stores. MODE: 0 bf16; 1 f32; 2 split KV (K-side bf16
// ldC=1024, V-side transposed [b][col][2048] u16x4 direct).
// ---------------------------------------------------------------------------
union __align__(16) SmemT {
  u16 stage[2][2][256 * 64];     // 128 KiB main-loop tiles
  float epi[128 * 260];          // 130 KiB epilogue C-staging
};

__device__ __forceinline__ s16x8 ldsfrag(const u16* p, int r, int c8) {
  return *(const s16x8*)&p[r * 64 + ((c8 ^ (r & 7)) << 3)];
}

template<int MAT, int LATE>
__device__ __forceinline__ void stage_chunk(const u16* __restrict__ gb, int row0,
                                            int K, int k0, u16* lbuf, int tid) {
#pragma unroll
  for (int i = 0; i < 2; ++i) {
    const int f = i * 512 + tid;
    const int rl = f >> 3, s = f & 7;
    int r;
    if (MAT == 0) r = (rl & 63) + ((rl >> 6) << 7) + (LATE ? 64 : 0);
    else          r = (rl & 31) + ((rl >> 5) << 6) + (LATE ? 32 : 0);
    const int gc = (s ^ (r & 7)) << 3;      // pre-swizzled global col chunk
    gld_lds16(gb + (long)(row0 + r) * K + k0 + gc, lbuf + r * 64 + s * 8);
  }
}

#define GFENCE asm volatile("" ::: "memory")

template<int QM>
__device__ __forceinline__ void load_af(s16x8 (&a)[4][2], const u16* lA,
                                        int wm, int lr, int lk) {
#pragma unroll
  for (int mi = 0; mi < 4; ++mi)
#pragma unroll
    for (int ks = 0; ks < 2; ++ks)
      a[mi][ks] = ldsfrag(lA, wm * 128 + QM * 64 + mi * 16 + lr, ks * 4 + lk);
}
template<int QN>
__device__ __forceinline__ void load_bg(s16x8 (&bb)[2][2], const u16* lB,
                                        int wn, int lr, int lk) {
#pragma unroll
  for (int ni = 0; ni < 2; ++ni)
#pragma unroll
    for (int ks = 0; ks < 2; ++ks)
      bb[ni][ks] = ldsfrag(lB, wn * 64 + QN * 32 + ni * 16 + lr, ks * 4 + lk);
}
// barrier, then MFMA cluster (no closing barrier)
template<int QM, int QN>
__device__ __forceinline__ void mfma16(f32x4 (&acc)[8][4],
                                       const s16x8 (&a)[4][2],
                                       const s16x8 (&bb)[2][2]) {
  GFENCE; __builtin_amdgcn_s_barrier(); GFENCE;
  __builtin_amdgcn_s_setprio(1);
#pragma unroll
  for (int mi = 0; mi < 4; ++mi)
#pragma unroll
    for (int ni = 0; ni < 2; ++ni) {
      acc[QM * 4 + mi][QN * 2 + ni] = __builtin_amdgcn_mfma_f32_16x16x32_bf16(
          a[mi][0], bb[ni][0], acc[QM * 4 + mi][QN * 2 + ni], 0, 0, 0);
      acc[QM * 4 + mi][QN * 2 + ni] = __builtin_amdgcn_mfma_f32_16x16x32_bf16(
          a[mi][1], bb[ni][1], acc[QM * 4 + mi][QN * 2 + ni], 0, 0, 0);
    }
  __builtin_amdgcn_s_setprio(0);
}

template<int CUR>
__device__ __forceinline__ void tile_body(
    int t, int NT, const u16* __restrict__ Ab, const u16* __restrict__ Bb,
    int bm, int bn, int K, u16 (&lds)[2][2][256 * 64], f32x4 (&acc)[8][4],
    int wm, int wn, int lr, int lk, int tid) {
  const u16* lA = lds[CUR][0];
  const u16* lB = lds[CUR][1];
  u16* nA = lds[CUR ^ 1][0];
  u16* nB = lds[CUR ^ 1][1];
  u16* cA = lds[CUR][0];
  u16* cB = lds[CUR][1];
  const int k1 = (t + 1) << 6, k2 = (t + 2) << 6;
  s16x8 af0[4][2], af1[4][2], bg0[2][2], bg1[2][2];
  // ph1
  load_af<0>(af0, lA, wm, lr, lk);
  load_bg<0>(bg0, lB, wn, lr, lk);
  if (t + 1 < NT) stage_chunk<0, 1>(Ab, bm, K, k1, nA, tid);
  mfma16<0, 0>(acc, af0, bg0);
  // ph2
  load_bg<1>(bg1, lB, wn, lr, lk);
  if (t + 1 < NT) stage_chunk<1, 1>(Bb, bn, K, k1, nB, tid);
  mfma16<0, 1>(acc, af0, bg1);
  // ph3
  load_af<1>(af1, lA, wm, lr, lk);
  if (t + 2 < NT) stage_chunk<0, 0>(Ab, bm, K, k2, cA, tid);
  mfma16<1, 1>(acc, af1, bg1);
  // ph4
  if (t + 2 < NT) stage_chunk<1, 0>(Bb, bn, K, k2, cB, tid);
  if (t + 2 < NT)      { asm volatile("s_waitcnt vmcnt(4)" ::: "memory"); }
  else if (t + 1 < NT) { asm volatile("s_waitcnt vmcnt(0)" ::: "memory"); }
  mfma16<1, 0>(acc, af1, bg0);
}

template<bool HAS_BIAS, int MODE>
__global__ __launch_bounds__(512, 1) void gemm256(
    const u16* __restrict__ A, const u16* __restrict__ B,
    const float* __restrict__ bias, const float* __restrict__ bias2,
    void* __restrict__ Cv, void* __restrict__ Cv2,
    int M, int N, int K, long sA, long sB, long sC, float scale) {
  __shared__ SmemT sm;
  // T1 swizzle: dispatch id -> XCD-contiguous chunk, z-major then x-major.
  const int nx = gridDim.x, ny = gridDim.y;
  const int did = blockIdx.x + nx * (blockIdx.y + ny * blockIdx.z);
  const int cpx = (nx * ny * gridDim.z) >> 3;       // all grids %8 == 0
  const int nf = (did & 7) * cpx + (did >> 3);
  const int b = nf / (nx * ny);
  const int rr = nf % (nx * ny);
  const int bm = (rr / ny) * 256;
  const int bn = (rr % ny) * 256;

  const u16* Ab = A + (long)b * sA;
  const u16* Bb = B + (long)b * sB;
  const int tid = threadIdx.x;
  const int lane = tid & 63, wave = tid >> 6;
  const int wm = wave >> 2, wn = wave & 3;
  const int lr = lane & 15, lk = lane >> 4;
  const int NT = K >> 6;                              // 16 or 32, always even

  f32x4 acc[8][4] = {};

  // prologue: tile0 all 4 chunks -> buf0, tile1 early chunks -> buf1
  stage_chunk<0, 0>(Ab, bm, K, 0, sm.stage[0][0], tid);
  stage_chunk<1, 0>(Bb, bn, K, 0, sm.stage[0][1], tid);
  stage_chunk<0, 1>(Ab, bm, K, 0, sm.stage[0][0], tid);
  stage_chunk<1, 1>(Bb, bn, K, 0, sm.stage[0][1], tid);
  if (NT > 1) {
    stage_chunk<0, 0>(Ab, bm, K, 64, sm.stage[1][0], tid);
    stage_chunk<1, 0>(Bb, bn, K, 64, sm.stage[1][1], tid);
    asm volatile("s_waitcnt vmcnt(4)" ::: "memory");
  } else {
    asm volatile("s_waitcnt vmcnt(0)" ::: "memory");
  }
  // (first barrier happens inside tile 0's mfma16<0,0>; reads before it are
  //  of tile 0 data which vmcnt above guarantees resident)
  GFENCE; __builtin_amdgcn_s_barrier(); GFENCE;

  for (int t = 0; t < NT; t += 2) {
    tile_body<0>(t,     NT, Ab, Bb, bm, bn, K, sm.stage, acc, wm, wn, lr, lk, tid);
    tile_body<1>(t + 1, NT, Ab, Bb, bm, bn, K, sm.stage, acc, wm, wn, lr, lk, tid);
  }

  // ---------------- epilogue ----------------
  const long cb = (long)b * sC;
  if (MODE == 2 && bn >= 1024) {
    // transposed V store: Cv2[batch][col][row], 2048 rows/batch
#pragma unroll
    for (int mi = 0; mi < 8; ++mi) {
#pragma unroll
      for (int ni = 0; ni < 4; ++ni) {
        const int row0 = bm + wm * 128 + mi * 16 + (lk << 2);
        const int col2 = (bn - 1024) + wn * 64 + ni * 16 + lr;
        const float bvx = HAS_BIAS ? bias2[col2] : 0.f;
        u16x4 pk;
#pragma unroll
        for (int j = 0; j < 4; ++j) pk[j] = f2bf(acc[mi][ni][j] * scale + bvx);
        const long ad = (long)(row0 >> 11) * (2048L * 1024) +
                        (long)col2 * 2048 + (row0 & 2047);
        *(u16x4*)&((u16*)Cv2)[ad] = pk;
      }
    }
  } else {
    const int ldC = (MODE == 2) ? 1024 : N;
    const int q = tid & 3, r = tid >> 2;          // r: 0..127
#pragma unroll
    for (int h = 0; h < 2; ++h) {
      GFENCE; __builtin_amdgcn_s_barrier(); GFENCE;  // lds free / prev reads done
      if (wm == h) {
#pragma unroll
        for (int mi = 0; mi < 8; ++mi)
#pragma unroll
          for (int ni = 0; ni < 4; ++ni) {
            const int c = wn * 64 + ni * 16 + lr;
            const float bvx = HAS_BIAS ? bias[bn + c] : 0.f;
#pragma unroll
            for (int j = 0; j < 4; ++j)
              sm.epi[(mi * 16 + (lk << 2) + j) * 260 + c] =
                  acc[mi][ni][j] * scale + bvx;
          }
      }
      GFENCE; __builtin_amdgcn_s_barrier(); GFENCE;
      const long grow = cb + (long)(bm + h * 128 + r) * ldC + bn;
#pragma unroll
      for (int ch = 0; ch < 8; ++ch) {
        const int c0 = q * 8 + ch * 32;
        const float4 x = *(const float4*)&sm.epi[r * 260 + c0];
        const float4 y = *(const float4*)&sm.epi[r * 260 + c0 + 4];
        if (MODE == 1) {
          *(float4*)&((float*)Cv)[grow + c0] = x;
          *(float4*)&((float*)Cv)[grow + c0 + 4] = y;
        } else {
          u16x8 pk;
          pk[0] = f2bf(x.x); pk[1] = f2bf(x.y);
          pk[2] = f2bf(x.z); pk[3] = f2bf(x.w);
          pk[4] = f2bf(y.x); pk[5] = f2bf(y.y);
          pk[6] = f2bf(y.z); pk[7] = f2bf(y.w);
          *(u16x8*)&((u16*)Cv)[grow + c0] = pk;
        }
      }
    }
  }
}

// ---------------------------------------------------------------------------
extern "C" void kernel_launch(void* const* d_in, const int* in_sizes, int n_in,
                              void* d_out, int out_size, void* d_ws, size_t ws_size,
                              hipStream_t stream) {
  const float* query = (const float*)d_in[0];   // [8,2048,1024]
  const float* kv    = (const float*)d_in[1];   // [8,2048,1024]
  const int*   mask  = (const int*)d_in[2];     // [8,2048,2048]
  const float* Wq = (const float*)d_in[3];
  const float* bq = (const float*)d_in[4];
  const float* Wk = (const float*)d_in[5];
  const float* bk = (const float*)d_in[6];
  const float* Wv = (const float*)d_in[7];
  const float* bv = (const float*)d_in[8];
  const float* Wo = (const float*)d_in[9];
  const float* bo = (const float*)d_in[10];
  float* out = (float*)d_out;

  char* ws = (char*)d_ws;
  const size_t MB = (size_t)1 << 20;
  u16* qbf  = (u16*)(ws + 0);          // 32MB query bf16; later reused as O
  u16* kvbf = (u16*)(ws + 32 * MB);    // 32MB kv bf16
  u16* wq   = (u16*)(ws + 64 * MB);    // 2MB  (wq,wk,wv,wo contiguous)
  u16* wk   = (u16*)(ws + 66 * MB);
  u16* wo   = (u16*)(ws + 70 * MB);
  u16* Q    = (u16*)(ws + 72 * MB);    // 32MB
  u16* Kb   = (u16*)(ws + 104 * MB);   // 32MB
  u16* Vt   = (u16*)(ws + 136 * MB);   // 32MB  [8][1024][2048] bf16
  u16* S    = (u16*)(ws + 168 * MB);   // 64MB  [8][2048][2048] bf16
  u16* O    = qbf;                     // [8][2048][1024] bf16 (qbf dead by then)

  const long sQK = (long)2048 * 1024;
  const long sS  = (long)2048 * 2048;

  // 1) converts
  cvt_f32_to_bf16<<<8192, 256, 0, stream>>>(query, qbf, 2097152);
  cvt_f32_to_bf16<<<8192, 256, 0, stream>>>(kv, kvbf, 2097152);
  cvt_w4<<<dim3(512, 4, 1), 256, 0, stream>>>(Wq, Wk, Wv, Wo, wq);

  // 2) Q projection: M=16384, N=1024, K=1024
  gemm256<true, 0><<<dim3(64, 4, 1), 512, 0, stream>>>(
      qbf, wq, bq, nullptr, Q, nullptr, 16384, 1024, 1024, 0, 0, 0, 1.f);

  // 3) merged K+V projection: N=2048 (B = wk||wv contiguous).
  gemm256<true, 2><<<dim3(64, 8, 1), 512, 0, stream>>>(
      kvbf, wk, bk, bv, Kb, Vt, 16384, 2048, 1024, 0, 0, 0, 1.f);

  // 4) S = (Q K^T) * 1/32 (mask applied in softmax)
  gemm256<false, 0><<<dim3(8, 8, 8), 512, 0, stream>>>(
      Q, Kb, nullptr, nullptr, S, nullptr, 2048, 2048, 1024, sQK, sQK, sS, 0.03125f);

  // 5) masked row softmax (in place on S)
  softmax_mask_rows<<<16384, 256, 0, stream>>>(S, mask);

  // 6) O = P @ V   (B = Vt [1024 n-rows][2048 k], batch stride sQK)
  gemm256<false, 0><<<dim3(8, 4, 8), 512, 0, stream>>>(
      S, Vt, nullptr, nullptr, O, nullptr, 2048, 1024, 2048, sS, sQK, sQK, 1.f);

  // 7) out = O @ Wo^T + bo   (fp32 output)
  gemm256<true, 1><<<dim3(64, 4, 1), 512, 0, stream>>>(
      O, wo, bo, nullptr, out, nullptr, 16384, 1024, 1024, 0, 0, 0, 1.f);
}

// Round 7
// 380.968 us; speedup vs baseline: 1.1410x; 1.1271x over previous
//
#include <hip/hip_runtime.h>
#include <hip/hip_bf16.h>
#include <stdint.h>

typedef unsigned short u16;
typedef short s16x8 __attribute__((ext_vector_type(8)));
typedef u16 u16x8 __attribute__((ext_vector_type(8)));
typedef u16 u16x4 __attribute__((ext_vector_type(4)));
typedef float f32x4 __attribute__((ext_vector_type(4)));

__device__ __forceinline__ u16 f2bf(float f) {
  union { float f; uint32_t u; } c; c.f = f;
  uint32_t u = c.u;
  u = u + 0x7fffu + ((u >> 16) & 1u);   // round-to-nearest-even
  return (u16)(u >> 16);
}
__device__ __forceinline__ float bf2f(u16 b) {
  union { uint32_t u; float f; } c; c.u = ((uint32_t)b) << 16;
  return c.f;
}

// async global->LDS, 16B per lane. LDS dest must be wave-uniform base + lane*16.
__device__ __forceinline__ void gld_lds16(const u16* g, u16* l) {
  __builtin_amdgcn_global_load_lds(
      (const __attribute__((address_space(1))) uint32_t*)g,
      (__attribute__((address_space(3))) uint32_t*)l,
      16, 0, 0);
}

// ---------------------------------------------------------------------------
// fp32 -> bf16 convert, 8 elems/thread
// ---------------------------------------------------------------------------
__global__ __launch_bounds__(256) void cvt_f32_to_bf16(
    const float* __restrict__ in, u16* __restrict__ out, long n8) {
  long i = (long)blockIdx.x * blockDim.x + threadIdx.x;
  if (i >= n8) return;
  const float4 a = ((const float4*)in)[i * 2];
  const float4 b = ((const float4*)in)[i * 2 + 1];
  u16x8 r;
  r[0] = f2bf(a.x); r[1] = f2bf(a.y); r[2] = f2bf(a.z); r[3] = f2bf(a.w);
  r[4] = f2bf(b.x); r[5] = f2bf(b.y); r[6] = f2bf(b.z); r[7] = f2bf(b.w);
  *(u16x8*)&out[i * 8] = r;
}

// 4 weight matrices (1024x1024 each) in one launch: blockIdx.y selects src
__global__ __launch_bounds__(256) void cvt_w4(
    const float* __restrict__ w0, const float* __restrict__ w1,
    const float* __restrict__ w2, const float* __restrict__ w3,
    u16* __restrict__ out) {
  const float* src = (blockIdx.y == 0) ? w0 : (blockIdx.y == 1) ? w1
                   : (blockIdx.y == 2) ? w2 : w3;
  const long i = (long)blockIdx.x * blockDim.x + threadIdx.x;
  const float4 a = ((const float4*)src)[i * 2];
  const float4 b = ((const float4*)src)[i * 2 + 1];
  u16x8 r;
  r[0] = f2bf(a.x); r[1] = f2bf(a.y); r[2] = f2bf(a.z); r[3] = f2bf(a.w);
  r[4] = f2bf(b.x); r[5] = f2bf(b.y); r[6] = f2bf(b.z); r[7] = f2bf(b.w);
  *(u16x8*)&out[(long)blockIdx.y * 1048576 + i * 8] = r;
}

// ---------------------------------------------------------------------------
// masked row softmax over 2048 cols, bf16 in/out (in place), fp32 math.
// ---------------------------------------------------------------------------
__global__ __launch_bounds__(256) void softmax_mask_rows(
    u16* __restrict__ S, const int* __restrict__ mask) {
  const long base = (long)blockIdx.x * 2048;
  const int tid = threadIdx.x;
  const int lane = tid & 63, wave = tid >> 6;
  u16x8 raw = *(const u16x8*)&S[base + tid * 8];
  const int4 m0 = ((const int4*)(mask + base))[tid * 2];
  const int4 m1 = ((const int4*)(mask + base))[tid * 2 + 1];
  float v[8];
  v[0] = m0.x ? bf2f(raw[0]) : -1e30f;
  v[1] = m0.y ? bf2f(raw[1]) : -1e30f;
  v[2] = m0.z ? bf2f(raw[2]) : -1e30f;
  v[3] = m0.w ? bf2f(raw[3]) : -1e30f;
  v[4] = m1.x ? bf2f(raw[4]) : -1e30f;
  v[5] = m1.y ? bf2f(raw[5]) : -1e30f;
  v[6] = m1.z ? bf2f(raw[6]) : -1e30f;
  v[7] = m1.w ? bf2f(raw[7]) : -1e30f;
  float m = v[0];
#pragma unroll
  for (int j = 1; j < 8; ++j) m = fmaxf(m, v[j]);
#pragma unroll
  for (int off = 32; off >= 1; off >>= 1) m = fmaxf(m, __shfl_xor(m, off));
  __shared__ float red[8];
  if (lane == 0) red[wave] = m;
  __syncthreads();
  m = fmaxf(fmaxf(red[0], red[1]), fmaxf(red[2], red[3]));
  float s = 0.f;
#pragma unroll
  for (int j = 0; j < 8; ++j) { v[j] = __expf(v[j] - m); s += v[j]; }
#pragma unroll
  for (int off = 32; off >= 1; off >>= 1) s += __shfl_xor(s, off);
  if (lane == 0) red[4 + wave] = s;
  __syncthreads();
  s = (red[4] + red[5]) + (red[6] + red[7]);
  const float inv = 1.f / s;
#pragma unroll
  for (int j = 0; j < 8; ++j) raw[j] = f2bf(v[j] * inv);
  *(u16x8*)&S[base + tid * 8] = raw;
}

// ---------------------------------------------------------------------------
// 128x128x64 GEMM (bt), m97/m103 structure (912 TF proven on this chip):
// 256 thr = 4 waves (2x2), per-wave 64x64 out (acc[4][4] f32x4), single-
// buffered 32 KiB LDS, 2 barriers per K-tile:
//   stage A+B (8x global_load_lds16) ; vmcnt(0) ; bar ; 2x(8 ds_read_b128 +
//   16 MFMA) ; bar
// Overlap comes from ~4 blocks/CU TLP (LDS 34 KiB incl. epi union), not
// intra-block pipelining. T2 chunk-XOR swizzle keeps ds_read conflict-free
// (strictly better than m97's 1.7e7 conflicts). T1 XCD-bijective remap.
// Epilogue: stage C through LDS ([64][132] f32, 2 halves) -> coalesced 16B
// stores. MODE: 0 bf16; 1 f32; 2 split KV (bn<1024 -> Kb ldC=1024;
// bn>=1024 -> Vt transposed [b][col][2048] u16x4 direct).
// ---------------------------------------------------------------------------
union __align__(16) SmemT {
  u16 stage[2][128 * 64];        // 32 KiB: A-tile, B-tile
  float epi[64 * 132];           // 33 KiB epilogue C-staging (half-tile)
};

__device__ __forceinline__ s16x8 ldsfrag(const u16* p, int r, int c8) {
  return *(const s16x8*)&p[r * 64 + ((c8 ^ (r & 7)) << 3)];
}

__device__ __forceinline__ void stage128(const u16* __restrict__ gb, int row0,
                                         int K, int k0, u16* lbuf, int tid) {
#pragma unroll
  for (int i = 0; i < 4; ++i) {
    const int f = i * 256 + tid;
    const int rl = f >> 3, s = f & 7;
    const int gc = (s ^ (rl & 7)) << 3;     // pre-swizzled global col chunk
    gld_lds16(gb + (long)(row0 + rl) * K + k0 + gc, lbuf + f * 8);
  }
}

template<bool HAS_BIAS, int MODE>
__global__ __launch_bounds__(256, 4) void gemm128(
    const u16* __restrict__ A, const u16* __restrict__ B,
    const float* __restrict__ bias, const float* __restrict__ bias2,
    void* __restrict__ Cv, void* __restrict__ Cv2,
    int M, int N, int K, long sA, long sB, long sC, float scale) {
  __shared__ SmemT sm;
  // T1 swizzle: dispatch id -> XCD-contiguous chunk (z-major, then m, then n)
  const int nx = gridDim.x, ny = gridDim.y;
  const int did = blockIdx.x + nx * (blockIdx.y + ny * blockIdx.z);
  const int cpx = (nx * ny * gridDim.z) >> 3;       // all grids %8 == 0
  const int nf = (did & 7) * cpx + (did >> 3);
  const int b = nf / (nx * ny);
  const int rr = nf % (nx * ny);
  const int bm = (rr / ny) * 128;
  const int bn = (rr % ny) * 128;

  const u16* Ab = A + (long)b * sA;
  const u16* Bb = B + (long)b * sB;
  const int tid = threadIdx.x;
  const int lane = tid & 63, wave = tid >> 6;
  const int wm = wave >> 1, wn = wave & 1;          // 2x2 waves, 64x64 each
  const int lr = lane & 15, lk = lane >> 4;
  const int NT = K >> 6;

  f32x4 acc[4][4] = {};

  for (int t = 0; t < NT; ++t) {
    stage128(Ab, bm, K, t << 6, sm.stage[0], tid);
    stage128(Bb, bn, K, t << 6, sm.stage[1], tid);
    asm volatile("s_waitcnt vmcnt(0)" ::: "memory");
    __syncthreads();
#pragma unroll
    for (int ks = 0; ks < 2; ++ks) {
      s16x8 af[4], bg[4];
#pragma unroll
      for (int mi = 0; mi < 4; ++mi)
        af[mi] = ldsfrag(sm.stage[0], wm * 64 + mi * 16 + lr, ks * 4 + lk);
#pragma unroll
      for (int ni = 0; ni < 4; ++ni)
        bg[ni] = ldsfrag(sm.stage[1], wn * 64 + ni * 16 + lr, ks * 4 + lk);
#pragma unroll
      for (int mi = 0; mi < 4; ++mi)
#pragma unroll
        for (int ni = 0; ni < 4; ++ni)
          acc[mi][ni] = __builtin_amdgcn_mfma_f32_16x16x32_bf16(
              af[mi], bg[ni], acc[mi][ni], 0, 0, 0);
    }
    __syncthreads();
  }

  // ---------------- epilogue ----------------
  const long cb = (long)b * sC;
  if (MODE == 2 && bn >= 1024) {
    // transposed V store: Cv2[batch][col][row], 2048 rows/batch
#pragma unroll
    for (int mi = 0; mi < 4; ++mi) {
#pragma unroll
      for (int ni = 0; ni < 4; ++ni) {
        const int row0 = bm + wm * 64 + mi * 16 + (lk << 2);
        const int col2 = (bn - 1024) + wn * 64 + ni * 16 + lr;
        const float bvx = HAS_BIAS ? bias2[col2] : 0.f;
        u16x4 pk;
#pragma unroll
        for (int j = 0; j < 4; ++j) pk[j] = f2bf(acc[mi][ni][j] * scale + bvx);
        const long ad = (long)(row0 >> 11) * (2048L * 1024) +
                        (long)col2 * 2048 + (row0 & 2047);
        *(u16x4*)&((u16*)Cv2)[ad] = pk;
      }
    }
  } else {
    const int ldC = (MODE == 2) ? 1024 : N;
    const int q = tid & 3, r = tid >> 2;            // r: 0..63
#pragma unroll
    for (int h = 0; h < 2; ++h) {
      __syncthreads();                              // prior LDS use complete
      if (wm == h) {
#pragma unroll
        for (int mi = 0; mi < 4; ++mi)
#pragma unroll
          for (int ni = 0; ni < 4; ++ni) {
            const int c = wn * 64 + ni * 16 + lr;
            const float bvx = HAS_BIAS ? bias[bn + c] : 0.f;
#pragma unroll
            for (int j = 0; j < 4; ++j)
              sm.epi[(mi * 16 + (lk << 2) + j) * 132 + c] =
                  acc[mi][ni][j] * scale + bvx;
          }
      }
      __syncthreads();
      const long grow = cb + (long)(bm + h * 64 + r) * ldC + bn;
#pragma unroll
      for (int ch = 0; ch < 4; ++ch) {
        const int c0 = q * 8 + ch * 32;
        const float4 x = *(const float4*)&sm.epi[r * 132 + c0];
        const float4 y = *(const float4*)&sm.epi[r * 132 + c0 + 4];
        if (MODE == 1) {
          *(float4*)&((float*)Cv)[grow + c0] = x;
          *(float4*)&((float*)Cv)[grow + c0 + 4] = y;
        } else {
          u16x8 pk;
          pk[0] = f2bf(x.x); pk[1] = f2bf(x.y);
          pk[2] = f2bf(x.z); pk[3] = f2bf(x.w);
          pk[4] = f2bf(y.x); pk[5] = f2bf(y.y);
          pk[6] = f2bf(y.z); pk[7] = f2bf(y.w);
          *(u16x8*)&((u16*)Cv)[grow + c0] = pk;
        }
      }
    }
  }
}

// ---------------------------------------------------------------------------
extern "C" void kernel_launch(void* const* d_in, const int* in_sizes, int n_in,
                              void* d_out, int out_size, void* d_ws, size_t ws_size,
                              hipStream_t stream) {
  const float* query = (const float*)d_in[0];   // [8,2048,1024]
  const float* kv    = (const float*)d_in[1];   // [8,2048,1024]
  const int*   mask  = (const int*)d_in[2];     // [8,2048,2048]
  const float* Wq = (const float*)d_in[3];
  const float* bq = (const float*)d_in[4];
  const float* Wk = (const float*)d_in[5];
  const float* bk = (const float*)d_in[6];
  const float* Wv = (const float*)d_in[7];
  const float* bv = (const float*)d_in[8];
  const float* Wo = (const float*)d_in[9];
  const float* bo = (const float*)d_in[10];
  float* out = (float*)d_out;

  char* ws = (char*)d_ws;
  const size_t MB = (size_t)1 << 20;
  u16* qbf  = (u16*)(ws + 0);          // 32MB query bf16; later reused as O
  u16* kvbf = (u16*)(ws + 32 * MB);    // 32MB kv bf16
  u16* wq   = (u16*)(ws + 64 * MB);    // 2MB  (wq,wk,wv,wo contiguous)
  u16* wk   = (u16*)(ws + 66 * MB);
  u16* wo   = (u16*)(ws + 70 * MB);
  u16* Q    = (u16*)(ws + 72 * MB);    // 32MB
  u16* Kb   = (u16*)(ws + 104 * MB);   // 32MB
  u16* Vt   = (u16*)(ws + 136 * MB);   // 32MB  [8][1024][2048] bf16
  u16* S    = (u16*)(ws + 168 * MB);   // 64MB  [8][2048][2048] bf16
  u16* O    = qbf;                     // [8][2048][1024] bf16 (qbf dead by then)

  const long sQK = (long)2048 * 1024;
  const long sS  = (long)2048 * 2048;

  // 1) converts
  cvt_f32_to_bf16<<<8192, 256, 0, stream>>>(query, qbf, 2097152);
  cvt_f32_to_bf16<<<8192, 256, 0, stream>>>(kv, kvbf, 2097152);
  cvt_w4<<<dim3(512, 4, 1), 256, 0, stream>>>(Wq, Wk, Wv, Wo, wq);

  // 2) Q projection: M=16384, N=1024, K=1024
  gemm128<true, 0><<<dim3(128, 8, 1), 256, 0, stream>>>(
      qbf, wq, bq, nullptr, Q, nullptr, 16384, 1024, 1024, 0, 0, 0, 1.f);

  // 3) merged K+V projection: N=2048 (B = wk||wv contiguous).
  gemm128<true, 2><<<dim3(128, 16, 1), 256, 0, stream>>>(
      kvbf, wk, bk, bv, Kb, Vt, 16384, 2048, 1024, 0, 0, 0, 1.f);

  // 4) S = (Q K^T) * 1/32 (mask applied in softmax)
  gemm128<false, 0><<<dim3(16, 16, 8), 256, 0, stream>>>(
      Q, Kb, nullptr, nullptr, S, nullptr, 2048, 2048, 1024, sQK, sQK, sS, 0.03125f);

  // 5) masked row softmax (in place on S)
  softmax_mask_rows<<<16384, 256, 0, stream>>>(S, mask);

  // 6) O = P @ V   (B = Vt [1024 n-rows][2048 k], batch stride sQK)
  gemm128<false, 0><<<dim3(16, 8, 8), 256, 0, stream>>>(
      S, Vt, nullptr, nullptr, O, nullptr, 2048, 1024, 2048, sS, sQK, sQK, 1.f);

  // 7) out = O @ Wo^T + bo   (fp32 output)
  gemm128<true, 1><<<dim3(128, 8, 1), 256, 0, stream>>>(
      O, wo, bo, nullptr, out, nullptr, 16384, 1024, 1024, 0, 0, 0, 1.f);
}